// Round 6
// baseline (310.524 us; speedup 1.0000x reference)
//
#include <hip/hip_runtime.h>
#include <stdint.h>
#include <stddef.h>

#define TEMP      0.05f
#define INV_TEMP  20.0f
#define MOMENTUM  0.2f
#define SMOOTH    0.1f
#define TAU_W     0.09f
#define NSAMP     100000
#define NFEAT     256
#define BATCH     256
#define SHIFT     20.0f     // |dot/TEMP| <= ~20.2 -> exp(l-20) safe
#define MT        64        // F rows per k_main block
#define TILES     1563      // ceil(NSAMP/MT)
#define NSHADOW   16
#define PREPB     256       // prep-role blocks in k_front
#define COPYB     2048      // copy-role blocks in k_front

typedef float  f32x4  __attribute__((ext_vector_type(4)));
typedef float  f32x2  __attribute__((ext_vector_type(2)));
typedef short  short8 __attribute__((ext_vector_type(8)));
typedef unsigned int u32x4 __attribute__((ext_vector_type(4)));

// fp32 -> bf16 round-to-nearest-even
__device__ __forceinline__ short f2bf(float f) {
    uint32_t u = __builtin_bit_cast(uint32_t, f);
    u = (u + 0x7fffu + ((u >> 16) & 1u)) >> 16;
    return (short)u;
}

__device__ __forceinline__ void mfma_bf16(f32x4& c, short8 a, short8 b) {
    asm("v_mfma_f32_16x16x32_bf16 %0, %1, %2, %0" : "+v"(c) : "v"(a), "v"(b));
}

// async global->LDS DMA, 16B per lane; lds dest is wave-uniform base (+lane*16 by HW)
__device__ __forceinline__ void gload_lds16(const short* g, short* l) {
    __builtin_amdgcn_global_load_lds(
        (const __attribute__((address_space(1))) unsigned int*)(const void*)g,
        (__attribute__((address_space(3))) unsigned int*)(void*)l,
        16, 0, 0);
}

__device__ __forceinline__ float block_reduce_sum256(float v, float* scratch) {
    for (int o = 32; o > 0; o >>= 1) v += __shfl_down(v, o, 64);
    int lane = threadIdx.x & 63, wid = threadIdx.x >> 6;
    if (lane == 0) scratch[wid] = v;
    __syncthreads();
    if (threadIdx.x == 0)
        scratch[4] = scratch[0] + scratch[1] + scratch[2] + scratch[3];
    __syncthreads();
    return scratch[4];
}

// ---------------------------------------------------------------------------
// K_FRONT: blocks [0,256) = prep role (normalize, XbF, d[b], zero Zs);
//          blocks [256, 256+COPYB) = copy role:
//   loop A: out[4j..4j+3] = F[4j-2..4j+1] -- ALIGNED 16B NT stores, the +2
//           misalignment moved to the read side (two natural f32x2 loads).
//   loop B: Fb fragment-linear bf16, one full 16B store per 8 source f32.
// ---------------------------------------------------------------------------
__global__ void __launch_bounds__(256)
k_front(const float* __restrict__ in1, const float* __restrict__ in2,
        const float* __restrict__ F, const int* __restrict__ tgt,
        float* __restrict__ x1n, short* __restrict__ XbF,
        float* __restrict__ dvec, float* __restrict__ Zs,
        short* __restrict__ Fb, float* outCopy) {
    int tid = threadIdx.x;
    if (blockIdx.x < PREPB) {
        // ---------------- prep role ----------------
        __shared__ float scratch[8];
        int b = blockIdx.x;
        int k = tid;
        int gid = b * NFEAT + k;
        if (gid < NSHADOW * BATCH * 3) Zs[gid] = 0.f;
        float v1 = in1[b * NFEAT + k];
        float v2 = in2[b * NFEAT + k];
        float n1 = block_reduce_sum256(v1 * v1, scratch);
        float n2 = block_reduce_sum256(v2 * v2, scratch);
        float x1 = v1 / fmaxf(sqrtf(n1), 1e-12f);
        float x2 = v2 / fmaxf(sqrtf(n2), 1e-12f);
        x1n[b * NFEAT + k] = x1;
        int w = b >> 5, r = b & 31;
        int cf = r >> 4, l15 = r & 15;
        int kk = k >> 5, lg = (k >> 3) & 3, j = k & 7;
        int lane = lg * 16 + l15;
        XbF[(((w * 4 + cf) * 8 + kk) * 64 + lane) * 8 + j]     = f2bf(x1);
        XbF[(((w * 4 + 2 + cf) * 8 + kk) * 64 + lane) * 8 + j] = f2bf(x2);
        int t = tgt[b];
        float dv = block_reduce_sum256(x1 * F[(size_t)t * NFEAT + k], scratch);
        if (k == 0) dvec[b] = dv;
        return;
    }
    // ---------------- copy role ----------------
    size_t gid    = (size_t)(blockIdx.x - PREPB) * 256 + tid;
    size_t stride = (size_t)COPYB * 256;
    const size_t total16 = (size_t)NSAMP * NFEAT / 4;   // 6,400,000

    if (outCopy != nullptr) {
        // loop A: shifted aligned copy
        for (size_t j = gid + 1; j < total16; j += stride) {
            f32x2 lo = *(const f32x2*)(F + 4 * j - 2);   // 8B aligned
            f32x2 hi = *(const f32x2*)(F + 4 * j);       // 16B aligned
            __builtin_nontemporal_store(f32x4{lo[0], lo[1], hi[0], hi[1]},
                                        (f32x4*)(outCopy + 4 * j));
        }
        if (gid == 0) {
            outCopy[2] = F[0];
            outCopy[3] = F[1];
            outCopy[total16 * 4]     = F[total16 * 4 - 2];
            outCopy[total16 * 4 + 1] = F[total16 * 4 - 1];
        }
    }
    // loop B: Fb fragment-linear bf16 (zero-fill pad rows)
    const size_t totalB = (size_t)TILES * MT * 32;      // 8-f32 units incl pad
    for (size_t u = gid; u < totalB; u += stride) {
        int row = (int)(u >> 5), c8 = (int)(u & 31);
        f32x4 v0 = {0.f, 0.f, 0.f, 0.f}, v1 = {0.f, 0.f, 0.f, 0.f};
        if (row < NSAMP) {
            v0 = *(const f32x4*)(F + (size_t)row * NFEAT + c8 * 8);
            v1 = *(const f32x4*)(F + (size_t)row * NFEAT + c8 * 8 + 4);
        }
        int tile = row >> 6, mf = (row >> 4) & 3, l15 = row & 15;
        int kk = c8 >> 2, lg = c8 & 3;
        uint32_t p0 = (uint32_t)(uint16_t)f2bf(v0[0]) | ((uint32_t)(uint16_t)f2bf(v0[1]) << 16);
        uint32_t p1 = (uint32_t)(uint16_t)f2bf(v0[2]) | ((uint32_t)(uint16_t)f2bf(v0[3]) << 16);
        uint32_t p2 = (uint32_t)(uint16_t)f2bf(v1[0]) | ((uint32_t)(uint16_t)f2bf(v1[1]) << 16);
        uint32_t p3 = (uint32_t)(uint16_t)f2bf(v1[2]) | ((uint32_t)(uint16_t)f2bf(v1[3]) << 16);
        size_t off = (size_t)tile * 16384 + (size_t)(((kk * 4 + mf) * 64 + lg * 16 + l15) * 8);
        *(u32x4*)(Fb + off) = (u32x4){p0, p1, p2, p3};
    }
}

// ---------------------------------------------------------------------------
// K0b (small-ws mode only): plain streaming copy F -> out+2, aligned stores.
// ---------------------------------------------------------------------------
__global__ void __launch_bounds__(256)
k_copy(const float* __restrict__ F, float* __restrict__ out) {
    const size_t total16 = (size_t)NSAMP * NFEAT / 4;
    size_t stride = (size_t)gridDim.x * 256;
    size_t gid = (size_t)blockIdx.x * 256 + threadIdx.x;
    for (size_t j = gid + 1; j < total16; j += stride) {
        f32x2 lo = *(const f32x2*)(F + 4 * j - 2);
        f32x2 hi = *(const f32x2*)(F + 4 * j);
        __builtin_nontemporal_store(f32x4{lo[0], lo[1], hi[0], hi[1]},
                                    (f32x4*)(out + 4 * j));
    }
    if (gid == 0) {
        out[2] = F[0];
        out[3] = F[1];
        out[total16 * 4]     = F[total16 * 4 - 2];
        out[total16 * 4 + 1] = F[total16 * 4 - 1];
    }
}

// ---------------------------------------------------------------------------
// K2: m97-style MFMA logits + shifted-exp reductions (unchanged from round 5).
// ---------------------------------------------------------------------------
__global__ void __launch_bounds__(512, 4)
k_main(const short* __restrict__ Fb, const short* __restrict__ XbF,
       float* __restrict__ Zs) {
    __shared__ short lfs[16384];   // 32 KB: [chunk=kk*4+mf][lane][8 bf16]
    int tid = threadIdx.x, w = tid >> 6, lane = tid & 63;
    size_t tbase = (size_t)blockIdx.x * 16384;

    #pragma unroll
    for (int j = 0; j < 4; ++j)
        gload_lds16(Fb + tbase + (size_t)((w * 4 + j) * 512 + lane * 8),
                    &lfs[(w * 4 + j) * 512]);
    __syncthreads();

    int l15 = lane & 15, lg = lane >> 4;
    int m0 = blockIdx.x * MT;
    f32x4 acc[4][4] = {};
    const short* xw = XbF + (size_t)w * 16384 + lane * 8;

    #pragma unroll
    for (int kk = 0; kk < 8; ++kk) {
        short8 bf0 = *(const short8*)(xw + (0 * 8 + kk) * 512);
        short8 bf1 = *(const short8*)(xw + (1 * 8 + kk) * 512);
        short8 bf2 = *(const short8*)(xw + (2 * 8 + kk) * 512);
        short8 bf3 = *(const short8*)(xw + (3 * 8 + kk) * 512);
        short8 a0 = *(const short8*)(&lfs[(kk * 4 + 0) * 512 + lane * 8]);
        short8 a1 = *(const short8*)(&lfs[(kk * 4 + 1) * 512 + lane * 8]);
        short8 a2 = *(const short8*)(&lfs[(kk * 4 + 2) * 512 + lane * 8]);
        short8 a3 = *(const short8*)(&lfs[(kk * 4 + 3) * 512 + lane * 8]);
        mfma_bf16(acc[0][0], a0, bf0); mfma_bf16(acc[0][1], a0, bf1);
        mfma_bf16(acc[0][2], a0, bf2); mfma_bf16(acc[0][3], a0, bf3);
        mfma_bf16(acc[1][0], a1, bf0); mfma_bf16(acc[1][1], a1, bf1);
        mfma_bf16(acc[1][2], a1, bf2); mfma_bf16(acc[1][3], a1, bf3);
        mfma_bf16(acc[2][0], a2, bf0); mfma_bf16(acc[2][1], a2, bf1);
        mfma_bf16(acc[2][2], a2, bf2); mfma_bf16(acc[2][3], a2, bf3);
        mfma_bf16(acc[3][0], a3, bf0); mfma_bf16(acc[3][1], a3, bf1);
        mfma_bf16(acc[3][2], a3, bf2); mfma_bf16(acc[3][3], a3, bf3);
    }

    int sh = (blockIdx.x & (NSHADOW - 1)) * BATCH;
    #pragma unroll
    for (int cf = 0; cf < 2; ++cf) {
        float z1 = 0.f, z2 = 0.f, s12 = 0.f;
        #pragma unroll
        for (int mf = 0; mf < 4; ++mf) {
            #pragma unroll
            for (int q = 0; q < 4; ++q) {
                int grow = m0 + mf * 16 + lg * 4 + q;
                if (grow < NSAMP) {
                    float l1 = acc[mf][cf][q] * INV_TEMP;
                    float e1 = __expf(l1 - SHIFT);
                    float e2 = __expf(acc[mf][cf + 2][q] * INV_TEMP - SHIFT);
                    z1 += e1; z2 += e2; s12 += e2 * l1;
                }
            }
        }
        z1  += __shfl_xor(z1, 16);  z1  += __shfl_xor(z1, 32);
        z2  += __shfl_xor(z2, 16);  z2  += __shfl_xor(z2, 32);
        s12 += __shfl_xor(s12, 16); s12 += __shfl_xor(s12, 32);
        if (lane < 16) {
            int b = w * 32 + cf * 16 + lane;
            atomicAdd(&Zs[sh + b], z1);
            atomicAdd(&Zs[NSHADOW * BATCH + sh + b], z2);
            atomicAdd(&Zs[2 * NSHADOW * BATCH + sh + b], s12);
        }
    }
}

// ---------------------------------------------------------------------------
// K3: blocks 0..255 -> cluster update; block 256 -> losses.
// ---------------------------------------------------------------------------
__global__ void k_tail(const float* __restrict__ F, const int* __restrict__ tgt,
                       const float* __restrict__ dvec, const float* __restrict__ x1n,
                       const float* __restrict__ Zs, float* __restrict__ out) {
    __shared__ float scratch[8];
    if (blockIdx.x == BATCH) {
        int b = threadIdx.x;
        float z1 = 0.f, z2 = 0.f, s12 = 0.f;
        #pragma unroll
        for (int j = 0; j < NSHADOW; ++j) {
            z1  += Zs[j * BATCH + b];
            z2  += Zs[NSHADOW * BATCH + j * BATCH + b];
            s12 += Zs[2 * NSHADOW * BATCH + j * BATCH + b];
        }
        float L1   = SHIFT + logf(z1);
        float lpt  = dvec[b] * INV_TEMP - L1;
        float ce12 = s12 / z2;
        float lc = -lpt;
        float ls = (1.f - SMOOTH) * (L1 - ce12) + SMOOTH * (-lpt);
        float sc = block_reduce_sum256(lc, scratch);
        float ss = block_reduce_sum256(ls, scratch);
        if (b == 0) {
            out[0] = sc / (float)BATCH;
            out[1] = ss / (float)BATCH;
        }
        return;
    }
    __shared__ int   stgt[BATCH];
    __shared__ float slog[BATCH];
    int b = blockIdx.x, k = threadIdx.x;
    stgt[k] = tgt[k];
    slog[k] = -dvec[k] * (1.0f / TAU_W);
    __syncthreads();
    int t = stgt[b];
    for (int bp = 0; bp < b; ++bp)
        if (stgt[bp] == t) return;   // uniform: first occurrence owns cluster t
    float m = -1e30f;
    for (int bp = 0; bp < BATCH; ++bp)
        if (stgt[bp] == t) m = fmaxf(m, slog[bp]);
    float denom = 0.f;
    for (int bp = 0; bp < BATCH; ++bp)
        if (stgt[bp] == t) denom += expf(slog[bp] - m);
    float wmean = 0.f;
    for (int bp = 0; bp < BATCH; ++bp)
        if (stgt[bp] == t)
            wmean += expf(slog[bp] - m) * x1n[bp * NFEAT + k];
    wmean /= denom;
    float upd = MOMENTUM * F[(size_t)t * NFEAT + k] + (1.f - MOMENTUM) * wmean;
    float nrm = block_reduce_sum256(upd * upd, scratch);
    out[2 + (size_t)t * NFEAT + k] = upd / fmaxf(sqrtf(nrm), 1e-12f);
}

extern "C" void kernel_launch(void* const* d_in, const int* in_sizes, int n_in,
                              void* d_out, int out_size, void* d_ws, size_t ws_size,
                              hipStream_t stream) {
    const float* in1 = (const float*)d_in[0];
    const float* in2 = (const float*)d_in[1];
    const float* F   = (const float*)d_in[2];
    const int*   tgt = (const int*)d_in[3];
    float* out = (float*)d_out;

    char* ws = (char*)d_ws;
    float* x1n = (float*)ws;                   // 256 KB
    short* XbF = (short*)(ws + 262144);        // 256 KB
    float* dv  = (float*)(ws + 524288);        // 1 KB
    float* Zs  = (float*)(ws + 525312);        // 48 KB
    const size_t FB_BYTES = (size_t)TILES * 32768;         // 51,216,384
    const size_t NEED     = 589824 + FB_BYTES;

    if (ws_size >= NEED) {
        short* Fb = (short*)(ws + 589824);
        hipLaunchKernelGGL(k_front, dim3(PREPB + COPYB), dim3(256), 0, stream,
                           in1, in2, F, tgt, x1n, XbF, dv, Zs, Fb, out);
        hipLaunchKernelGGL(k_main, dim3(TILES), dim3(512), 0, stream, Fb, XbF, Zs);
        hipLaunchKernelGGL(k_tail, dim3(BATCH + 1), dim3(256), 0, stream,
                           F, tgt, dv, x1n, Zs, out);
    } else {
        // overlay Fb in the tail of d_out; write the true copy after k_main
        short* Fb = (short*)((char*)d_out + 51183616);
        hipLaunchKernelGGL(k_front, dim3(PREPB + COPYB), dim3(256), 0, stream,
                           in1, in2, F, tgt, x1n, XbF, dv, Zs, Fb, (float*)nullptr);
        hipLaunchKernelGGL(k_main, dim3(TILES), dim3(512), 0, stream, Fb, XbF, Zs);
        hipLaunchKernelGGL(k_copy, dim3(2048), dim3(256), 0, stream, F, out);
        hipLaunchKernelGGL(k_tail, dim3(BATCH + 1), dim3(256), 0, stream,
                           F, tgt, dv, x1n, Zs, out);
    }
}